// Round 8
// baseline (267.151 us; speedup 1.0000x reference)
//
#include <hip/hip_runtime.h>

#define C 128        // IN_CH == OUT_CH
#define NPB 16       // nodes per node-pre block
#define NSLAB 8      // one bucket slab per XCD (slab id = real XCC_ID)
#define CAP8 16      // per-slab bucket capacity = one 64B line (mean 8.2, sd 2.9; ovf path)
#define OVF_MAX 65536
#define EPT 4        // edges per thread in scatter

typedef int   vi4 __attribute__((ext_vector_type(4)));   // native vectors: nontemporal-ok
typedef float vf4 __attribute__((ext_vector_type(4)));

__device__ __forceinline__ unsigned bf16_bits(float x) {   // round-to-nearest-even
    unsigned u = __float_as_uint(x);
    u += 0x7FFFu + ((u >> 16) & 1u);
    return u >> 16;
}
__device__ __forceinline__ float bf16f(unsigned short b) {
    return __uint_as_float(((unsigned)b) << 16);
}
// HW_REG_XCC_ID = hwreg 20; simm16 = 20 | (0<<6) | ((32-1)<<11) = 63508. [measured: learn_hip m09]
__device__ __forceinline__ int xcd_id() {
    return (int)(__builtin_amdgcn_s_getreg(63508) & 7u);
}

// Heterogeneous kernel: blocks [0, SB) scatter edges into XCD-private padded-CSR
// slabs (slab = REAL XCC_ID -> every bucket line has exactly one writing XCD,
// stays in that XCD's L2 until the end-of-kernel flush). Blocks [SB, SB+PB)
// compute P = x@W1[:C] (bf16) and Q = x@W1[C:] (fp32).
__global__ void fused_pre_kernel(const float* __restrict__ x, const float* __restrict__ W1,
                                 unsigned short* __restrict__ P16, float* __restrict__ Q,
                                 const int* __restrict__ ei, const float* __restrict__ attr,
                                 int* __restrict__ cursor, int* __restrict__ ovf_cnt,
                                 int2* __restrict__ ovf, unsigned* __restrict__ sorted,
                                 int N, int E, int SB) {
    if ((int)blockIdx.x < SB) {
        const int slab = xcd_id();
        int* __restrict__ cur = cursor + (size_t)slab * N;
        unsigned* __restrict__ sl = sorted + ((size_t)slab * N) * CAP8;
        const int base = (blockIdx.x * 256 + threadIdx.x) * EPT;
        if (base >= E) return;
        if (base + EPT <= E) {
            // non-temporal streaming reads: don't evict bucket lines from L2
            const vi4 r0 = __builtin_nontemporal_load((const vi4*)(ei + base));
            const vi4 c0 = __builtin_nontemporal_load((const vi4*)(ei + (size_t)E + base));
            const vf4 a0 = __builtin_nontemporal_load((const vf4*)(attr + base));
            const int rows[EPT] = {r0.x, r0.y, r0.z, r0.w};
            const int cols[EPT] = {c0.x, c0.y, c0.z, c0.w};
            const float as[EPT] = {a0.x, a0.y, a0.z, a0.w};
            int pos[EPT];
#pragma unroll
            for (int j = 0; j < EPT; ++j)
                pos[j] = atomicAdd(&cur[cols[j]], 1);
#pragma unroll
            for (int j = 0; j < EPT; ++j) {
                const unsigned v = (bf16_bits(as[j]) << 16) | (unsigned)rows[j];
                if (pos[j] < CAP8) {
                    sl[((size_t)cols[j] << 4) + pos[j]] = v;
                } else {
                    const int o = atomicAdd(ovf_cnt, 1);
                    if (o < OVF_MAX) ovf[o] = make_int2(cols[j], (int)v);
                }
            }
        } else {
            for (int e = base; e < E; ++e) {
                const int row = ei[e], colv = ei[(size_t)E + e];
                const int pos = atomicAdd(&cur[colv], 1);
                const unsigned v = (bf16_bits(attr[e]) << 16) | (unsigned)row;
                if (pos < CAP8) sl[((size_t)colv << 4) + pos] = v;
                else {
                    const int o = atomicAdd(ovf_cnt, 1);
                    if (o < OVF_MAX) ovf[o] = make_int2(colv, (int)v);
                }
            }
        }
    } else {
        // node pre-GEMM: 16 nodes/block, 256 threads (half -> P bf16, half -> Q fp32)
        __shared__ float xs[NPB][C];
        const int pb = blockIdx.x - SB;
        const int n0 = pb * NPB;
        const int tt = threadIdx.x & (C - 1);
        const int half = threadIdx.x >> 7;
        for (int i = threadIdx.x; i < NPB * C; i += 256) {
            const int gi = n0 * C + i;
            xs[0][i] = (gi < N * C) ? __builtin_nontemporal_load(x + gi) : 0.f;
        }
        __syncthreads();
        const float* __restrict__ Wb = W1 + (half ? (C * C) : 0) + tt;
        float acc[NPB] = {};
        for (int k = 0; k < C; ++k) {
            const float w = Wb[k * C];
#pragma unroll
            for (int j = 0; j < NPB; ++j)
                acc[j] = fmaf(xs[j][k], w, acc[j]);
        }
#pragma unroll
        for (int j = 0; j < NPB; ++j)
            if (n0 + j < N) {
                if (half) Q[(size_t)(n0 + j) * C + tt] = acc[j];
                else      P16[(size_t)(n0 + j) * C + tt] = (unsigned short)bf16_bits(acc[j]);
            }
    }
}

struct G { ushort4 p; float a; };
__device__ __forceinline__ G gat(unsigned v, const unsigned short* __restrict__ P16, int ch4) {
    G g;
    g.p = *(const ushort4*)(P16 + (((size_t)(v & 0xFFFFu)) << 7) + (ch4 << 2));
    g.a = __uint_as_float(v & 0xFFFF0000u);
    return g;
}
__device__ __forceinline__ void upd(float4& acc, const G& g, const float4& qb) {
    acc.x += fmaxf(fmaf(g.a, bf16f(g.p.x), qb.x), 0.f);
    acc.y += fmaxf(fmaf(g.a, bf16f(g.p.y), qb.y), 0.f);
    acc.z += fmaxf(fmaf(g.a, bf16f(g.p.z), qb.z), 0.f);
    acc.w += fmaxf(fmaf(g.a, bf16f(g.p.w), qb.w), 0.f);
}

// Fused aggregation + output GEMM. 2 nodes per 256-thread block.
// Thread (j = t>>7, slice = (t>>5)&3, ch4 = t&31): slice handles slabs {slice, slice+4}
// INTERLEAVED (8 independent bf16 P-gathers in flight). LDS-reduce slices -> H,
// then k-sliced W2 matmul with float4 loads, LDS-reduce -> out.
__global__ void agg_out_kernel(const unsigned* __restrict__ sorted, const int* __restrict__ cursor,
                               const unsigned short* __restrict__ P16, const float* __restrict__ Q,
                               const float* __restrict__ b1, const float* __restrict__ W2,
                               const float* __restrict__ b2,
                               const int* __restrict__ ovf_cnt, const int2* __restrict__ ovf,
                               float* __restrict__ out, int N) {
    __shared__ float4 part[2][4][32];
    __shared__ float hs[2][C];
    const int t = threadIdx.x;
    const int j = t >> 7;
    const int slice = (t >> 5) & 3;
    const int ch4 = t & 31;
    const int n = blockIdx.x * 2 + j;

    float4 acc = make_float4(0.f, 0.f, 0.f, 0.f);
    float4 qb = acc;
    int deg = 0;
    if (n < N) {
        int cnts[NSLAB];
#pragma unroll
        for (int s = 0; s < NSLAB; ++s) {
            cnts[s] = cursor[(size_t)s * N + n];
            deg += cnts[s];
        }
        const float4 q4  = *(const float4*)(Q + (size_t)n * C + (ch4 << 2));
        const float4 b14 = *(const float4*)(b1 + (ch4 << 2));
        qb = make_float4(q4.x + b14.x, q4.y + b14.y, q4.z + b14.z, q4.w + b14.w);

        const int sA = slice, sB = slice + 4;
        const int cA = min(cnts[sA], CAP8), cB = min(cnts[sB], CAP8);
        const unsigned* __restrict__ bufA = sorted + (((size_t)sA * N + n) << 4);
        const unsigned* __restrict__ bufB = sorted + (((size_t)sB * N + n) << 4);
        int iA = 0, iB = 0;
        // interleaved main loop: 8 gathers in flight
        while (iA + 4 <= cA && iB + 4 <= cB) {
            const uint4 vA = *(const uint4*)(bufA + iA);
            const uint4 vB = *(const uint4*)(bufB + iB);
            const G g0 = gat(vA.x, P16, ch4), g1 = gat(vA.y, P16, ch4);
            const G g2 = gat(vA.z, P16, ch4), g3 = gat(vA.w, P16, ch4);
            const G g4 = gat(vB.x, P16, ch4), g5 = gat(vB.y, P16, ch4);
            const G g6 = gat(vB.z, P16, ch4), g7 = gat(vB.w, P16, ch4);
            upd(acc, g0, qb); upd(acc, g1, qb); upd(acc, g2, qb); upd(acc, g3, qb);
            upd(acc, g4, qb); upd(acc, g5, qb); upd(acc, g6, qb); upd(acc, g7, qb);
            iA += 4; iB += 4;
        }
        for (; iA + 4 <= cA; iA += 4) {
            const uint4 v = *(const uint4*)(bufA + iA);
            const G g0 = gat(v.x, P16, ch4), g1 = gat(v.y, P16, ch4);
            const G g2 = gat(v.z, P16, ch4), g3 = gat(v.w, P16, ch4);
            upd(acc, g0, qb); upd(acc, g1, qb); upd(acc, g2, qb); upd(acc, g3, qb);
        }
        for (; iB + 4 <= cB; iB += 4) {
            const uint4 v = *(const uint4*)(bufB + iB);
            const G g0 = gat(v.x, P16, ch4), g1 = gat(v.y, P16, ch4);
            const G g2 = gat(v.z, P16, ch4), g3 = gat(v.w, P16, ch4);
            upd(acc, g0, qb); upd(acc, g1, qb); upd(acc, g2, qb); upd(acc, g3, qb);
        }
        for (; iA < cA; ++iA) { const G g = gat(bufA[iA], P16, ch4); upd(acc, g, qb); }
        for (; iB < cB; ++iB) { const G g = gat(bufB[iB], P16, ch4); upd(acc, g, qb); }

        if (slice == 0) {   // overflow entries (rare: ~0.3% of buckets spill)
            const int oc = min(*ovf_cnt, OVF_MAX);
            for (int o = 0; o < oc; ++o) {
                const int2 v = ovf[o];
                if (v.x == n) { const G g = gat((unsigned)v.y, P16, ch4); upd(acc, g, qb); }
            }
        }
    }
    part[j][slice][ch4] = acc;
    __syncthreads();
    if (slice == 0 && n < N) {
        const float4 r0 = part[j][0][ch4], r1 = part[j][1][ch4];
        const float4 r2 = part[j][2][ch4], r3 = part[j][3][ch4];
        float4 h;
        h.x = r0.x + r1.x + r2.x + r3.x;
        h.y = r0.y + r1.y + r2.y + r3.y;
        h.z = r0.z + r1.z + r2.z + r3.z;
        h.w = r0.w + r1.w + r2.w + r3.w;
        *(float4*)(&hs[j][ch4 << 2]) = h;
    }
    __syncthreads();
    // k-sliced matmul: slice covers k in [slice*32, slice*32+32)
    float4 o = make_float4(0.f, 0.f, 0.f, 0.f);
    if (n < N) {
        const int k0 = slice << 5;
#pragma unroll 8
        for (int k = k0; k < k0 + 32; ++k) {
            const float hv = hs[j][k];
            const float4 w = *(const float4*)(W2 + (size_t)k * C + (ch4 << 2));
            o.x = fmaf(hv, w.x, o.x);
            o.y = fmaf(hv, w.y, o.y);
            o.z = fmaf(hv, w.z, o.z);
            o.w = fmaf(hv, w.w, o.w);
        }
    }
    __syncthreads();            // before reusing `part`
    part[j][slice][ch4] = o;
    __syncthreads();
    if (slice == 0 && n < N) {
        const float4 r0 = part[j][0][ch4], r1 = part[j][1][ch4];
        const float4 r2 = part[j][2][ch4], r3 = part[j][3][ch4];
        const float4 b24 = *(const float4*)(b2 + (ch4 << 2));
        const float d = (float)deg;
        float4 res;
        res.x = fmaf(d, b24.x, r0.x + r1.x + r2.x + r3.x);
        res.y = fmaf(d, b24.y, r0.y + r1.y + r2.y + r3.y);
        res.z = fmaf(d, b24.z, r0.z + r1.z + r2.z + r3.z);
        res.w = fmaf(d, b24.w, r0.w + r1.w + r2.w + r3.w);
        *(float4*)(out + (size_t)n * C + (ch4 << 2)) = res;
    }
}

extern "C" void kernel_launch(void* const* d_in, const int* in_sizes, int n_in,
                              void* d_out, int out_size, void* d_ws, size_t ws_size,
                              hipStream_t stream) {
    const float* x    = (const float*)d_in[0];
    const int*   ei   = (const int*)d_in[1];
    const float* attr = (const float*)d_in[2];
    const float* W1   = (const float*)d_in[3];
    const float* b1   = (const float*)d_in[4];
    const float* W2   = (const float*)d_in[5];
    const float* b2   = (const float*)d_in[6];
    float* out = (float*)d_out;

    const int N = in_sizes[0] / C;
    const int E = in_sizes[2];

    char* ws = (char*)d_ws;
    unsigned short* P16 = (unsigned short*)ws;  ws += (size_t)N * C * sizeof(unsigned short);
    ws = (char*)(((uintptr_t)ws + 15) & ~(uintptr_t)15);
    float*    Q       = (float*)ws;     ws += (size_t)N * C * sizeof(float);
    unsigned* sorted  = (unsigned*)ws;  ws += (size_t)NSLAB * N * CAP8 * sizeof(unsigned);
    int2*     ovf     = (int2*)ws;      ws += (size_t)OVF_MAX * sizeof(int2);
    int*      cursor  = (int*)ws;       ws += (size_t)NSLAB * N * sizeof(int);
    int*      ovf_cnt = (int*)ws;

    // zero per-slab cursors + ovf_cnt (contiguous)
    (void)hipMemsetAsync(cursor, 0, ((size_t)NSLAB * N + 1) * sizeof(int), stream);

    const int SB = (E + 256 * EPT - 1) / (256 * EPT);
    const int PB = (N + NPB - 1) / NPB;
    fused_pre_kernel<<<SB + PB, 256, 0, stream>>>(x, W1, P16, Q, ei, attr,
                                                  cursor, ovf_cnt, ovf, sorted, N, E, SB);
    agg_out_kernel<<<(N + 1) / 2, 256, 0, stream>>>(sorted, cursor, P16, Q, b1, W2, b2,
                                                    ovf_cnt, ovf, out, N);
}

// Round 9
// 161.296 us; speedup vs baseline: 1.6563x; 1.6563x over previous
//
#include <hip/hip_runtime.h>

#define C 128        // IN_CH == OUT_CH
#define NPB 16       // nodes per node-pre block
#define NSLAB 8      // one bucket slab per XCD (slab id = real XCC_ID)
#define CAP8 24      // per-slab bucket capacity (Poisson(8): P(>24) ~ 1e-6 -> ovf empty)
#define OVF_MAX 65536
#define EPT 4        // edges per thread in scatter

typedef int   vi4 __attribute__((ext_vector_type(4)));   // native vectors: nontemporal-ok
typedef float vf4 __attribute__((ext_vector_type(4)));

__device__ __forceinline__ unsigned bf16_bits(float x) {   // round-to-nearest-even
    unsigned u = __float_as_uint(x);
    u += 0x7FFFu + ((u >> 16) & 1u);
    return u >> 16;
}
__device__ __forceinline__ float bf16f(unsigned short b) {
    return __uint_as_float(((unsigned)b) << 16);
}
// HW_REG_XCC_ID = hwreg 20; simm16 = 20 | (0<<6) | ((32-1)<<11) = 63508. [measured: learn_hip m09]
__device__ __forceinline__ int xcd_id() {
    return (int)(__builtin_amdgcn_s_getreg(63508) & 7u);
}

// Heterogeneous kernel: blocks [0, SB) scatter edges into XCD-private padded-CSR
// slabs (slab = REAL XCC_ID -> every bucket/cursor line has exactly one writing
// XCD). Blocks [SB, SB+PB) compute P = x@W1[:C] (bf16) and Q = x@W1[C:] (fp32).
__global__ void fused_pre_kernel(const float* __restrict__ x, const float* __restrict__ W1,
                                 unsigned short* __restrict__ P16, float* __restrict__ Q,
                                 const int* __restrict__ ei, const float* __restrict__ attr,
                                 int* __restrict__ cursor, int* __restrict__ ovf_cnt,
                                 int2* __restrict__ ovf, unsigned* __restrict__ sorted,
                                 int N, int E, int SB) {
    if ((int)blockIdx.x < SB) {
        const int slab = xcd_id();
        int* __restrict__ cur = cursor + (size_t)slab * N;
        unsigned* __restrict__ sl = sorted + ((size_t)slab * N) * CAP8;
        const int base = (blockIdx.x * 256 + threadIdx.x) * EPT;
        if (base >= E) return;
        if (base + EPT <= E) {
            // non-temporal streaming reads: don't evict bucket lines from L2
            const vi4 r0 = __builtin_nontemporal_load((const vi4*)(ei + base));
            const vi4 c0 = __builtin_nontemporal_load((const vi4*)(ei + (size_t)E + base));
            const vf4 a0 = __builtin_nontemporal_load((const vf4*)(attr + base));
            const int rows[EPT] = {r0.x, r0.y, r0.z, r0.w};
            const int cols[EPT] = {c0.x, c0.y, c0.z, c0.w};
            const float as[EPT] = {a0.x, a0.y, a0.z, a0.w};
            int pos[EPT];
#pragma unroll
            for (int j = 0; j < EPT; ++j)
                pos[j] = atomicAdd(&cur[cols[j]], 1);
#pragma unroll
            for (int j = 0; j < EPT; ++j) {
                const unsigned v = (bf16_bits(as[j]) << 16) | (unsigned)rows[j];
                if (pos[j] < CAP8) {
                    sl[(size_t)cols[j] * CAP8 + pos[j]] = v;
                } else {
                    const int o = atomicAdd(ovf_cnt, 1);
                    if (o < OVF_MAX) ovf[o] = make_int2(cols[j], (int)v);
                }
            }
        } else {
            for (int e = base; e < E; ++e) {
                const int row = ei[e], colv = ei[(size_t)E + e];
                const int pos = atomicAdd(&cur[colv], 1);
                const unsigned v = (bf16_bits(attr[e]) << 16) | (unsigned)row;
                if (pos < CAP8) sl[(size_t)colv * CAP8 + pos] = v;
                else {
                    const int o = atomicAdd(ovf_cnt, 1);
                    if (o < OVF_MAX) ovf[o] = make_int2(colv, (int)v);
                }
            }
        }
    } else {
        // node pre-GEMM: 16 nodes/block, 256 threads (half -> P bf16, half -> Q fp32)
        __shared__ float xs[NPB][C];
        const int pb = blockIdx.x - SB;
        const int n0 = pb * NPB;
        const int tt = threadIdx.x & (C - 1);
        const int half = threadIdx.x >> 7;
        for (int i = threadIdx.x; i < NPB * C; i += 256) {
            const int gi = n0 * C + i;
            xs[0][i] = (gi < N * C) ? __builtin_nontemporal_load(x + gi) : 0.f;
        }
        __syncthreads();
        const float* __restrict__ Wb = W1 + (half ? (C * C) : 0) + tt;
        float acc[NPB] = {};
        for (int k = 0; k < C; ++k) {
            const float w = Wb[k * C];
#pragma unroll
            for (int j = 0; j < NPB; ++j)
                acc[j] = fmaf(xs[j][k], w, acc[j]);
        }
#pragma unroll
        for (int j = 0; j < NPB; ++j)
            if (n0 + j < N) {
                if (half) Q[(size_t)(n0 + j) * C + tt] = acc[j];
                else      P16[(size_t)(n0 + j) * C + tt] = (unsigned short)bf16_bits(acc[j]);
            }
    }
}

struct G { ushort4 p; float a; };
__device__ __forceinline__ G gat(unsigned v, const unsigned short* __restrict__ P16, int ch4) {
    G g;
    g.p = *(const ushort4*)(P16 + (((size_t)(v & 0xFFFFu)) << 7) + (ch4 << 2));
    g.a = __uint_as_float(v & 0xFFFF0000u);
    return g;
}
__device__ __forceinline__ void upd(float4& acc, const G& g, const float4& qb) {
    acc.x += fmaxf(fmaf(g.a, bf16f(g.p.x), qb.x), 0.f);
    acc.y += fmaxf(fmaf(g.a, bf16f(g.p.y), qb.y), 0.f);
    acc.z += fmaxf(fmaf(g.a, bf16f(g.p.z), qb.z), 0.f);
    acc.w += fmaxf(fmaf(g.a, bf16f(g.p.w), qb.w), 0.f);
}

// Fused aggregation + output GEMM. 2 nodes per 256-thread block.
// Thread (j = t>>7, slice = (t>>5)&3, ch4 = t&31): slice handles slabs {slice, slice+4},
// lane owns 4 channels via ushort4 bf16 gathers of P. LDS-reduce slices -> H,
// then k-sliced W2 matmul with float4 loads, LDS-reduce -> out.
__global__ void agg_out_kernel(const unsigned* __restrict__ sorted, const int* __restrict__ cursor,
                               const unsigned short* __restrict__ P16, const float* __restrict__ Q,
                               const float* __restrict__ b1, const float* __restrict__ W2,
                               const float* __restrict__ b2,
                               const int* __restrict__ ovf_cnt, const int2* __restrict__ ovf,
                               float* __restrict__ out, int N) {
    __shared__ float4 part[2][4][32];
    __shared__ float hs[2][C];
    const int t = threadIdx.x;
    const int j = t >> 7;
    const int slice = (t >> 5) & 3;
    const int ch4 = t & 31;
    const int n = blockIdx.x * 2 + j;

    float4 acc = make_float4(0.f, 0.f, 0.f, 0.f);
    float4 qb = acc;
    int deg = 0;
    if (n < N) {
        int cnts[NSLAB];
#pragma unroll
        for (int s = 0; s < NSLAB; ++s) {
            cnts[s] = cursor[(size_t)s * N + n];
            deg += cnts[s];
        }
        const float4 q4  = *(const float4*)(Q + (size_t)n * C + (ch4 << 2));
        const float4 b14 = *(const float4*)(b1 + (ch4 << 2));
        qb = make_float4(q4.x + b14.x, q4.y + b14.y, q4.z + b14.z, q4.w + b14.w);
#pragma unroll
        for (int si = 0; si < 2; ++si) {
            const int s = slice + (si << 2);
            const int cs = min(cnts[s], CAP8);
            const unsigned* __restrict__ buf = sorted + ((size_t)s * N + n) * CAP8;
            int i = 0;
            for (; i + 4 <= cs; i += 4) {
                const uint4 v = *(const uint4*)(buf + i);
                const G g0 = gat(v.x, P16, ch4), g1 = gat(v.y, P16, ch4);
                const G g2 = gat(v.z, P16, ch4), g3 = gat(v.w, P16, ch4);
                upd(acc, g0, qb); upd(acc, g1, qb); upd(acc, g2, qb); upd(acc, g3, qb);
            }
            for (; i < cs; ++i) {
                const G g = gat(buf[i], P16, ch4);
                upd(acc, g, qb);
            }
        }
        const int oc = min(*ovf_cnt, OVF_MAX);
        if (oc > 0 && slice == 0) {   // overflow: statistically empty (P ~ 1e-6/bucket)
            for (int o = 0; o < oc; ++o) {
                const int2 v = ovf[o];
                if (v.x == n) { const G g = gat((unsigned)v.y, P16, ch4); upd(acc, g, qb); }
            }
        }
    }
    part[j][slice][ch4] = acc;
    __syncthreads();
    if (slice == 0 && n < N) {
        const float4 r0 = part[j][0][ch4], r1 = part[j][1][ch4];
        const float4 r2 = part[j][2][ch4], r3 = part[j][3][ch4];
        float4 h;
        h.x = r0.x + r1.x + r2.x + r3.x;
        h.y = r0.y + r1.y + r2.y + r3.y;
        h.z = r0.z + r1.z + r2.z + r3.z;
        h.w = r0.w + r1.w + r2.w + r3.w;
        *(float4*)(&hs[j][ch4 << 2]) = h;
    }
    __syncthreads();
    // k-sliced matmul: slice covers k in [slice*32, slice*32+32)
    float4 o = make_float4(0.f, 0.f, 0.f, 0.f);
    if (n < N) {
        const int k0 = slice << 5;
#pragma unroll 8
        for (int k = k0; k < k0 + 32; ++k) {
            const float hv = hs[j][k];
            const float4 w = *(const float4*)(W2 + (size_t)k * C + (ch4 << 2));
            o.x = fmaf(hv, w.x, o.x);
            o.y = fmaf(hv, w.y, o.y);
            o.z = fmaf(hv, w.z, o.z);
            o.w = fmaf(hv, w.w, o.w);
        }
    }
    __syncthreads();            // before reusing `part`
    part[j][slice][ch4] = o;
    __syncthreads();
    if (slice == 0 && n < N) {
        const float4 r0 = part[j][0][ch4], r1 = part[j][1][ch4];
        const float4 r2 = part[j][2][ch4], r3 = part[j][3][ch4];
        const float4 b24 = *(const float4*)(b2 + (ch4 << 2));
        const float d = (float)deg;
        float4 res;
        res.x = fmaf(d, b24.x, r0.x + r1.x + r2.x + r3.x);
        res.y = fmaf(d, b24.y, r0.y + r1.y + r2.y + r3.y);
        res.z = fmaf(d, b24.z, r0.z + r1.z + r2.z + r3.z);
        res.w = fmaf(d, b24.w, r0.w + r1.w + r2.w + r3.w);
        *(float4*)(out + (size_t)n * C + (ch4 << 2)) = res;
    }
}

extern "C" void kernel_launch(void* const* d_in, const int* in_sizes, int n_in,
                              void* d_out, int out_size, void* d_ws, size_t ws_size,
                              hipStream_t stream) {
    const float* x    = (const float*)d_in[0];
    const int*   ei   = (const int*)d_in[1];
    const float* attr = (const float*)d_in[2];
    const float* W1   = (const float*)d_in[3];
    const float* b1   = (const float*)d_in[4];
    const float* W2   = (const float*)d_in[5];
    const float* b2   = (const float*)d_in[6];
    float* out = (float*)d_out;

    const int N = in_sizes[0] / C;
    const int E = in_sizes[2];

    char* ws = (char*)d_ws;
    unsigned short* P16 = (unsigned short*)ws;  ws += (size_t)N * C * sizeof(unsigned short);
    ws = (char*)(((uintptr_t)ws + 15) & ~(uintptr_t)15);
    float*    Q       = (float*)ws;     ws += (size_t)N * C * sizeof(float);
    unsigned* sorted  = (unsigned*)ws;  ws += (size_t)NSLAB * N * CAP8 * sizeof(unsigned);
    int2*     ovf     = (int2*)ws;      ws += (size_t)OVF_MAX * sizeof(int2);
    int*      cursor  = (int*)ws;       ws += (size_t)NSLAB * N * sizeof(int);
    int*      ovf_cnt = (int*)ws;

    // zero per-slab cursors + ovf_cnt (contiguous)
    (void)hipMemsetAsync(cursor, 0, ((size_t)NSLAB * N + 1) * sizeof(int), stream);

    const int SB = (E + 256 * EPT - 1) / (256 * EPT);
    const int PB = (N + NPB - 1) / NPB;
    fused_pre_kernel<<<SB + PB, 256, 0, stream>>>(x, W1, P16, Q, ei, attr,
                                                  cursor, ovf_cnt, ovf, sorted, N, E, SB);
    agg_out_kernel<<<(N + 1) / 2, 256, 0, stream>>>(sorted, cursor, P16, Q, b1, W2, b2,
                                                    ovf_cnt, ovf, out, N);
}